// Round 4
// baseline (15854.688 us; speedup 1.0000x reference)
//
#include <hip/hip_runtime.h>

#define Bb 256
#define Tt 512
#define Dd 512
#define Hh 512
#define KTOT 1024
#define FOURH 2048

typedef __attribute__((ext_vector_type(8))) short bf16x8;
typedef __attribute__((ext_vector_type(4))) float f32x4;

__device__ __forceinline__ unsigned short f2bf(float f) {
    union { float f; unsigned u; } x; x.f = f;
    unsigned u = x.u;
    unsigned r = u + 0x7FFFu + ((u >> 16) & 1u);
    return (unsigned short)(r >> 16);
}
__device__ __forceinline__ float bf2f(unsigned short s) {
    union { unsigned u; float f; } x; x.u = ((unsigned)s) << 16;
    return x.f;
}

// Transpose + split W = [Wx; Wh] (K=1024 rows, N=2048 cols) into
// WT_hi/WT_lo layout [N=2048][K=1024] bf16 (k-contiguous per output column).
__global__ void prep_w(const float* __restrict__ Wx, const float* __restrict__ Wh,
                       unsigned short* __restrict__ WT_hi, unsigned short* __restrict__ WT_lo) {
    __shared__ float tile[32][33];
    int n0 = (blockIdx.x & 63) * 32;
    int k0 = (blockIdx.x >> 6) * 32;
    int tx = threadIdx.x & 31;
    int ty = threadIdx.x >> 5;
    for (int q = 0; q < 4; ++q) {
        int k = k0 + ty + q * 8;
        int n = n0 + tx;
        float v = (k < Dd) ? Wx[(size_t)k * FOURH + n] : Wh[(size_t)(k - Dd) * FOURH + n];
        tile[ty + q * 8][tx] = v;
    }
    __syncthreads();
    for (int q = 0; q < 4; ++q) {
        int nl = ty + q * 8;
        int kl = tx;
        float v = tile[kl][nl];
        unsigned short hi = f2bf(v);
        unsigned short lo = f2bf(v - bf2f(hi));
        size_t o = (size_t)(n0 + nl) * KTOT + (size_t)(k0 + kl);
        WT_hi[o] = hi;
        WT_lo[o] = lo;
    }
}

__global__ void init_state(float* __restrict__ c_st,
                           unsigned short* __restrict__ h_bufs) {
    int i = blockIdx.x * blockDim.x + threadIdx.x;
    if (i < Bb * Hh) c_st[i] = 0.f;
    // 4 regions: h_hi[0], h_lo[0], h_hi[1], h_lo[1] contiguous (4 * 128K shorts)
    for (int q = 0; q < 4; ++q)
        if (i < Bb * Hh) h_bufs[(size_t)q * Bb * Hh + i] = 0;
}

// One timestep. Grid: 512 WGs x 512 threads (2 WG/CU -> 4 waves/SIMD).
// WG tile: 16 batch-rows x 16 h-cols x 4 gates. 8 waves:
//   gate = w8 & 3, khalf = w8 >> 2.
//   khalf=0 waves: K 0..511   (X half, fp32 loads + inline hi/lo split)
//   khalf=1 waves: K 512..1023 (h half, bf16 hi/lo direct loads from READ buffer)
// h is DOUBLE-BUFFERED across steps: read h_r*, write h_w* -> no intra-launch race.
// XCD-aligned cols: xcd = bx&7 owns col_groups xcd*4 .. xcd*4+3
// => 1 MB W slice (hi+lo) L2-resident per XCD for all 512 steps.
// Split-3 bf16 MFMA with 3 INDEPENDENT accumulator chains (hh, hl, lh).
__global__ __launch_bounds__(512) void lstm_step4(
    const float* __restrict__ X, const int* __restrict__ lengths,
    const unsigned short* __restrict__ WT_hi, const unsigned short* __restrict__ WT_lo,
    const float* __restrict__ bias,
    float* __restrict__ c_st,
    const unsigned short* __restrict__ h_r_hi, const unsigned short* __restrict__ h_r_lo,
    unsigned short* __restrict__ h_w_hi, unsigned short* __restrict__ h_w_lo,
    float* __restrict__ out, int t)
{
    __shared__ float zbuf[8][16][17];

    const int bx = blockIdx.x;
    const int xcd = bx & 7;
    const int rem = bx >> 3;            // 0..63
    const int m0 = (rem & 15) * 16;     // 16 row tiles
    const int col_group = xcd * 4 + (rem >> 4);   // 0..31
    const int hc0 = col_group * 16;
    const int tid = threadIdx.x;
    const int w8 = tid >> 6;            // 0..7
    const int lane = tid & 63;
    const int gate = w8 & 3;
    const int khalf = w8 >> 2;

    f32x4 ahh = (f32x4){0.f, 0.f, 0.f, 0.f};
    f32x4 ahl = (f32x4){0.f, 0.f, 0.f, 0.f};
    f32x4 alh = (f32x4){0.f, 0.f, 0.f, 0.f};

    const int colk = gate * 512 + hc0 + (lane & 15);
    const size_t bbase = (size_t)colk * KTOT;
    const int klo = (lane >> 4) * 8;    // 0,8,16,24
    const int row = m0 + (lane & 15);

    if (khalf == 0) {
        const float* xrow = &X[((size_t)row * Tt + t) * Dd];
        const unsigned short* bhp = &WT_hi[bbase];
        const unsigned short* blp = &WT_lo[bbase];
#pragma unroll
        for (int ks = 0; ks < 16; ++ks) {
            const int kk = ks * 32 + klo;
            const float4 v0 = *(const float4*)&xrow[kk];
            const float4 v1 = *(const float4*)&xrow[kk + 4];
            float vv[8] = {v0.x, v0.y, v0.z, v0.w, v1.x, v1.y, v1.z, v1.w};
            bf16x8 ah, al;
#pragma unroll
            for (int e = 0; e < 8; ++e) {
                unsigned short hi = f2bf(vv[e]);
                ah[e] = (short)hi;
                al[e] = (short)f2bf(vv[e] - bf2f(hi));
            }
            const bf16x8 bh = *(const bf16x8*)&bhp[kk];
            const bf16x8 bl = *(const bf16x8*)&blp[kk];
            ahh = __builtin_amdgcn_mfma_f32_16x16x32_bf16(ah, bh, ahh, 0, 0, 0);
            ahl = __builtin_amdgcn_mfma_f32_16x16x32_bf16(ah, bl, ahl, 0, 0, 0);
            alh = __builtin_amdgcn_mfma_f32_16x16x32_bf16(al, bh, alh, 0, 0, 0);
        }
    } else {
        const unsigned short* hrh = &h_r_hi[(size_t)row * Hh];
        const unsigned short* hrl = &h_r_lo[(size_t)row * Hh];
        const unsigned short* bhp = &WT_hi[bbase + 512];
        const unsigned short* blp = &WT_lo[bbase + 512];
#pragma unroll
        for (int ks = 0; ks < 16; ++ks) {
            const int kk = ks * 32 + klo;
            const bf16x8 ah = *(const bf16x8*)&hrh[kk];
            const bf16x8 al = *(const bf16x8*)&hrl[kk];
            const bf16x8 bh = *(const bf16x8*)&bhp[kk];
            const bf16x8 bl = *(const bf16x8*)&blp[kk];
            ahh = __builtin_amdgcn_mfma_f32_16x16x32_bf16(ah, bh, ahh, 0, 0, 0);
            ahl = __builtin_amdgcn_mfma_f32_16x16x32_bf16(ah, bl, ahl, 0, 0, 0);
            alh = __builtin_amdgcn_mfma_f32_16x16x32_bf16(al, bh, alh, 0, 0, 0);
        }
    }

    const f32x4 z = ahh + ahl + alh;

    // C/D layout: col = lane&15, row = (lane>>4)*4 + r
#pragma unroll
    for (int r = 0; r < 4; ++r)
        zbuf[w8][(lane >> 4) * 4 + r][lane & 15] = z[r];
    __syncthreads();

    // gates + state update: 16 rows x 16 cols = 256 elems, threads 0..255
    if (tid < 256) {
        const int r = tid >> 4;
        const int j = tid & 15;
        const int row_g = m0 + r;
        const int col_g = hc0 + j;
        float zi = zbuf[0][r][j] + zbuf[4][r][j] + bias[col_g];
        float zf = zbuf[1][r][j] + zbuf[5][r][j] + bias[512 + col_g];
        float zg = zbuf[2][r][j] + zbuf[6][r][j] + bias[1024 + col_g];
        float zo = zbuf[3][r][j] + zbuf[7][r][j] + bias[1536 + col_g];
        float ig = 1.f / (1.f + expf(-zi));
        float fg = 1.f / (1.f + expf(-zf));
        float gg = tanhf(zg);
        float og = 1.f / (1.f + expf(-zo));
        const size_t idx = (size_t)row_g * Hh + col_g;
        float cn = fg * c_st[idx] + ig * gg;
        float hn = og * tanhf(cn);
        c_st[idx] = cn;
        unsigned short hh = f2bf(hn);
        h_w_hi[idx] = hh;
        h_w_lo[idx] = f2bf(hn - bf2f(hh));
        int len = lengths[row_g];
        int oidx = len - 1; if (oidx < 0) oidx = 0;
        if (t == oidx) out[idx] = hn;
    }
}

extern "C" void kernel_launch(void* const* d_in, const int* in_sizes, int n_in,
                              void* d_out, int out_size, void* d_ws, size_t ws_size,
                              hipStream_t stream) {
    const float* X = (const float*)d_in[0];
    const int* lengths = (const int*)d_in[1];
    const float* Wx = (const float*)d_in[2];
    const float* Wh = (const float*)d_in[3];
    const float* bias = (const float*)d_in[4];
    float* out = (float*)d_out;

    char* ws = (char*)d_ws;
    unsigned short* WT_hi = (unsigned short*)ws;                               // 4 MB
    unsigned short* WT_lo = (unsigned short*)(ws + (4u << 20));                // 4 MB
    float* c_st = (float*)(ws + (8u << 20));                                   // 512 KB
    // h double buffers: [hi0][lo0][hi1][lo1], each 256 KB
    unsigned short* h_base = (unsigned short*)(ws + (8u << 20) + (512u << 10));
    const size_t HB = (size_t)Bb * Hh;
    unsigned short* h_hi0 = h_base;
    unsigned short* h_lo0 = h_base + HB;
    unsigned short* h_hi1 = h_base + 2 * HB;
    unsigned short* h_lo1 = h_base + 3 * HB;

    hipLaunchKernelGGL(prep_w, dim3(2048), dim3(256), 0, stream, Wx, Wh, WT_hi, WT_lo);
    hipLaunchKernelGGL(init_state, dim3(512), dim3(256), 0, stream, c_st, h_base);
    for (int t = 0; t < Tt; ++t) {
        const bool even = (t & 1) == 0;
        hipLaunchKernelGGL(lstm_step4, dim3(512), dim3(512), 0, stream,
                           X, lengths, WT_hi, WT_lo, bias, c_st,
                           even ? h_hi0 : h_hi1, even ? h_lo0 : h_lo1,
                           even ? h_hi1 : h_hi0, even ? h_lo1 : h_lo0,
                           out, t);
    }
}